// Round 18
// baseline (88.026 us; speedup 1.0000x reference)
//
#include <hip/hip_runtime.h>
#include <cstdint>
#include <cstddef>

// Problem constants (from reference): N=16384, D=256.
#define NV 16384
#define DD 256
#define TPB 1024           // k_mis threads (16 waves), 1 vertex/thread/block
#define BLK 1024
#define PCAP 7             // in-block lower-neighbor cap (fallback exists)
#define HROW 24            // u16 slots per vertex in hi_g: [0]=count, [1..23]=higher nbrs
#define NPASS 512          // spin cap per barrier round (common case: 1 round/block)

// compiler memory barrier: forces LDS re-reads across passes WITHOUT ordering
// the loads within a pass against each other
#define CFENCE() asm volatile("" ::: "memory")

// ---------------------------------------------------------------------------
// K_prep (parallel, one pass over nbr): per vertex v emit
//  - pend_g[v] (uint4): in-1024-block lower neighbors as u16 offsets
//      x = count | e0<<16 ; y = e1|e2<<16 ; z = e3|e4<<16 ; w = e5|e6<<16
//  - hi_g[v*HROW..]: u16 slots[24]: [0]=count, [1..23]=higher-nbr ids,
//    packed in registers, stored as 3 coalesced uint4
// ---------------------------------------------------------------------------
__global__ __launch_bounds__(256)
void k_prep(const int* __restrict__ nbr, const int* __restrict__ deg,
            int maxdeg, int n, uint4* __restrict__ pend_g,
            unsigned short* __restrict__ hi_g)
{
    int v = blockIdx.x * 256 + threadIdx.x;
    if (v >= n) return;
    const int b  = v & ~(BLK - 1);
    const int dv = deg[v];
    const int* __restrict__ row = nbr + (size_t)v * (size_t)maxdeg;
    unsigned w0 = 0, w1 = 0, w2 = 0, w3 = 0;
    unsigned g0=0,g1=0,g2=0,g3=0,g4=0,g5=0,g6=0,g7=0,g8=0,g9=0,g10=0,g11=0;
    int cnt = 0, hic = 0;
    for (int k = 0; k < dv; ++k) {
        int j = row[k];
        if (j > v) {
            unsigned e = (unsigned)j;
            switch (hic) {      // entry i at u16 slot 1+i: word (1+i)>>1, half (1+i)&1
                case 0:  g0  |= e << 16; break;
                case 1:  g1  |= e; break;   case 2:  g1  |= e << 16; break;
                case 3:  g2  |= e; break;   case 4:  g2  |= e << 16; break;
                case 5:  g3  |= e; break;   case 6:  g3  |= e << 16; break;
                case 7:  g4  |= e; break;   case 8:  g4  |= e << 16; break;
                case 9:  g5  |= e; break;   case 10: g5  |= e << 16; break;
                case 11: g6  |= e; break;   case 12: g6  |= e << 16; break;
                case 13: g7  |= e; break;   case 14: g7  |= e << 16; break;
                case 15: g8  |= e; break;   case 16: g8  |= e << 16; break;
                case 17: g9  |= e; break;   case 18: g9  |= e << 16; break;
                case 19: g10 |= e; break;   case 20: g10 |= e << 16; break;
                case 21: g11 |= e; break;   case 22: g11 |= e << 16; break;
                default: break;
            }
            ++hic;
        } else if (j >= b) {
            unsigned val = (unsigned)(j - b);
            switch (cnt) {
                case 0: w0 |= val << 16; break;
                case 1: w1 |= val;       break;
                case 2: w1 |= val << 16; break;
                case 3: w2 |= val;       break;
                case 4: w2 |= val << 16; break;
                case 5: w3 |= val;       break;
                case 6: w3 |= val << 16; break;
                default: break;
            }
            ++cnt;
        }
    }
    g0 |= (unsigned)(hic > 0xffff ? 0xffff : hic);
    uint4* hq = (uint4*)(hi_g + (size_t)v * HROW);   // 48B rows, 16B-aligned
    hq[0] = make_uint4(g0, g1, g2, g3);
    hq[1] = make_uint4(g4, g5, g6, g7);
    hq[2] = make_uint4(g8, g9, g10, g11);
    w0 |= (unsigned)(cnt > 0xffff ? 0xffff : cnt);
    pend_g[v] = make_uint4(w0, w1, w2, w3);
}

// ---------------------------------------------------------------------------
// K_mis: lexicographic greedy MIS, single WG of 1024 threads (16 waves), PUSH.
// st: 0=unknown, 1=head, 2=nonhead (monotone -> LDS races benign).
// NEW vs R12/R17: each wave SPINS until all its lanes are decided (in-block
// deps point to lower indices; the smallest undecided vertex can always
// decide, and its owner wave is still spinning -> provable progress), so a
// block needs ONE barrier instead of ~4: ~16 barriers total vs ~70.
// The F-protocol remains as a safety net (NPASS spin cap).
// ---------------------------------------------------------------------------
__global__ __launch_bounds__(TPB, 4)
void k_mis(const int* __restrict__ nbr, const int* __restrict__ deg,
           int maxdeg, int n,
           const uint4* __restrict__ pend_g, const unsigned short* __restrict__ hi_g,
           int* __restrict__ headlist, float* __restrict__ out_tail)
{
    __shared__ __align__(16) unsigned char st[NV];
    __shared__ int s_ws[TPB / 64];
    __shared__ int F[3];
    const int t    = threadIdx.x;
    const int lane = t & 63;
    const int wid  = t >> 6;

    ((uint4*)st)[t] = make_uint4(0u, 0u, 0u, 0u);   // 1024*16B == NV
    if (t < 3) F[t] = 0;
    __syncthreads();

    // prefetch block 0 (pend + hi row + deg), register double-buffered
    uint4 pv = make_uint4(0,0,0,0), h0 = pv, h1 = pv, h2 = pv;
    int   dv = 0;
    if (t < n) {
        pv = pend_g[t];
        const uint4* hp = (const uint4*)(hi_g + (size_t)t * HROW);
        h0 = hp[0]; h1 = hp[1]; h2 = hp[2];
        dv = deg[t];
    }
    int r = 0;

    for (int b = 0; b < n; b += BLK) {
        const int v = b + t;
        // prefetch next block; stays in flight across the drain-free barriers
        uint4 pn = make_uint4(0,0,0,0), n0 = pn, n1 = pn, n2 = pn;
        int   dn = 0;
        {
            int vn = b + BLK + t;
            if (vn < n) {
                pn = pend_g[vn];
                const uint4* hp = (const uint4*)(hi_g + (size_t)vn * HROW);
                n0 = hp[0]; n1 = hp[1]; n2 = hp[2];
                dn = deg[vn];
            }
        }

        const int np = pv.x & 0xffff;
        const int e0 = pv.x >> 16,    e1 = pv.y & 0xffff, e2 = pv.y >> 16;
        const int e3 = pv.z & 0xffff, e4 = pv.z >> 16;
        const int e5 = pv.w & 0xffff, e6 = pv.w >> 16;
        const int hic = (int)(h0.x & 0xffff);
        const int* __restrict__ row = nbr + (size_t)v * (size_t)maxdeg;

        int my = (v < n) ? 0 : 2;
        for (;; ++r) {
            if (t == 0) F[(r + 1) % 3] = 0;
            // spin until this wave's lanes are all decided (cap = safety net)
            for (int pass = 0; pass < NPASS; ++pass) {
                if (my == 0) {
                    // own status always; probe batch only when needed
                    int qv = st[v];
                    int q0 = 0, q1 = 0, q2 = 0, q3 = 0, q4 = 0, q5 = 0, q6 = 0;
                    if (np > 0 && np <= PCAP) {
                        q0 = st[b + e0]; q1 = st[b + e1]; q2 = st[b + e2];
                        q3 = st[b + e3]; q4 = st[b + e4]; q5 = st[b + e5];
                        q6 = st[b + e6];
                    }
                    if (qv != 0) { my = 2; }
                    else {
                        bool anyH = false; int undec = 0;
                        if (np <= PCAP) {
                            if (np > 0) { anyH |= (q0 == 1); undec += (q0 == 0); }
                            if (np > 1) { anyH |= (q1 == 1); undec += (q1 == 0); }
                            if (np > 2) { anyH |= (q2 == 1); undec += (q2 == 0); }
                            if (np > 3) { anyH |= (q3 == 1); undec += (q3 == 0); }
                            if (np > 4) { anyH |= (q4 == 1); undec += (q4 == 0); }
                            if (np > 5) { anyH |= (q5 == 1); undec += (q5 == 0); }
                            if (np > 6) { anyH |= (q6 == 1); undec += (q6 == 0); }
                        } else {
                            for (int k = 0; k < dv; ++k) {
                                int j = row[k];
                                if (j >= b && j < v) {
                                    int q = st[j];
                                    anyH |= (q == 1); undec += (q == 0);
                                }
                            }
                        }
                        if (anyH) { my = 2; st[v] = 2; }
                        else if (undec == 0) {
                            my = 1;
                            st[v] = 1;
                            if (hic <= HROW - 1) {
                                // push from registers: entry i at u16 slot 1+i
                                #define PUSHE(word, sh, k) if ((k) < hic) st[((word) >> (sh)) & 0xffffu] = 2
                                PUSHE(h0.x,16, 0); PUSHE(h0.y, 0, 1); PUSHE(h0.y,16, 2);
                                PUSHE(h0.z, 0, 3); PUSHE(h0.z,16, 4); PUSHE(h0.w, 0, 5);
                                PUSHE(h0.w,16, 6);
                                PUSHE(h1.x, 0, 7); PUSHE(h1.x,16, 8); PUSHE(h1.y, 0, 9);
                                PUSHE(h1.y,16,10); PUSHE(h1.z, 0,11); PUSHE(h1.z,16,12);
                                PUSHE(h1.w, 0,13); PUSHE(h1.w,16,14);
                                PUSHE(h2.x, 0,15); PUSHE(h2.x,16,16); PUSHE(h2.y, 0,17);
                                PUSHE(h2.y,16,18); PUSHE(h2.z, 0,19); PUSHE(h2.z,16,20);
                                PUSHE(h2.w, 0,21); PUSHE(h2.w,16,22);
                                #undef PUSHE
                            } else {
                                for (int k = 0; k < dv; ++k) {
                                    int j = row[k];
                                    if (j > v) st[j] = 2;
                                }
                            }
                        }
                    }
                }
                if (__ballot(my == 0) == 0ULL) break;   // wave done -> barrier
                CFENCE();   // force genuine LDS re-reads next pass
            }
            if (my == 0) F[r % 3] = 1;   // only if spin cap was exhausted
            // drain-free barrier: LDS visible, global prefetch stays in flight
            asm volatile("s_waitcnt lgkmcnt(0)\n\ts_barrier" ::: "memory");
            if (F[r % 3] == 0) { ++r; break; }
        }
        pv = pn; h0 = n0; h1 = n1; h2 = n2; dv = dn;
    }

    // ---- epilogue: count heads, scan, emit headlist / head_mask / count ----
    uint4 qq = ((const uint4*)st)[t];          // thread t owns bytes [16t,16t+16)
    int cnt = __popc(qq.x & 0x01010101u) + __popc(qq.y & 0x01010101u)
            + __popc(qq.z & 0x01010101u) + __popc(qq.w & 0x01010101u);
    int c = cnt;
    #pragma unroll
    for (int off = 1; off < 64; off <<= 1) {
        int x = __shfl_up(c, off);
        if (lane >= off) c += x;
    }
    if (lane == 63) s_ws[wid] = c;
    __syncthreads();
    int wexcl = 0, tot = 0;
    #pragma unroll
    for (int w = 0; w < TPB / 64; ++w) {
        int s = s_ws[w];
        tot += s;
        if (w < wid) wexcl += s;
    }
    int excl = wexcl + (c - cnt);
    #pragma unroll
    for (int i = 0; i < 16; ++i) {
        int v = t * 16 + i;
        if (st[v] == 1) { headlist[excl] = v; ++excl; }
    }
    for (int i = t; i < NV / 4; i += TPB) {
        unsigned w = ((const unsigned*)st)[i];
        float4 f;
        f.x = (float)(w & 1u);         f.y = (float)((w >> 8) & 1u);
        f.z = (float)((w >> 16) & 1u); f.w = (float)((w >> 24) & 1u);
        ((float4*)out_tail)[i] = f;
    }
    if (t == 0) out_tail[n] = (float)tot;
}

// ---------------------------------------------------------------------------
// K_avg (fused owner+avg): one 64-lane wave per output row.
// Waves [0,tot): cluster mean for h=headlist[w]. Candidate j in row(h):
// owner(j)==h <=> j has NO adjacent head < h (disqualification scan).
// Waves [tot,n): zero-fill the row (replaces the memset).
// ---------------------------------------------------------------------------
__global__ __launch_bounds__(256)
void k_avg(const float* __restrict__ vert, const int* __restrict__ nbr,
           const int* __restrict__ deg, int maxdeg, int n,
           const int* __restrict__ headlist,
           const float* __restrict__ tail, float* __restrict__ out)
{
    const int w    = (blockIdx.x * 256 + threadIdx.x) >> 6;
    const int lane = threadIdx.x & 63;
    if (w >= n) return;
    const int tot  = (int)tail[n];
    if (w >= tot) {
        reinterpret_cast<float4*>(out + (size_t)w * DD)[lane] = make_float4(0.f, 0.f, 0.f, 0.f);
        return;
    }
    const int h = headlist[w];

    const int dh = deg[h];
    const int* __restrict__ row = nbr + (size_t)h * (size_t)maxdeg;

    float4 acc = reinterpret_cast<const float4*>(vert + (size_t)h * DD)[lane];
    int cnt = 1;

    for (int k0 = 0; k0 < dh; k0 += 64) {
        int k = k0 + lane;
        int j = (k < dh) ? row[k] : -1;
        bool mem = false;
        if (j > h && tail[j] == 0.0f) {        // nonhead, higher candidate
            const int dj = deg[j];
            const int* __restrict__ rj = nbr + (size_t)j * (size_t)maxdeg;
            bool bad = false;
            for (int kk = 0; kk < dj; ++kk) {
                int u = rj[kk];
                if (u < h && tail[u] != 0.0f) { bad = true; break; }
            }
            mem = !bad;
        }
        unsigned long long m = __ballot(mem);
        cnt += __popcll(m);
        while (m) {
            int bit = __ffsll((long long)m) - 1;
            m &= (m - 1);
            int jj = __shfl(j, bit);
            float4 rr = reinterpret_cast<const float4*>(vert + (size_t)jj * DD)[lane];
            acc.x += rr.x; acc.y += rr.y; acc.z += rr.z; acc.w += rr.w;
        }
    }
    const float inv = 1.0f / (float)cnt;
    float4 res;
    res.x = acc.x * inv; res.y = acc.y * inv;
    res.z = acc.z * inv; res.w = acc.w * inv;
    reinterpret_cast<float4*>(out + (size_t)w * DD)[lane] = res;
}

// ---------------------------------------------------------------------------
extern "C" void kernel_launch(void* const* d_in, const int* in_sizes, int n_in,
                              void* d_out, int out_size, void* d_ws, size_t ws_size,
                              hipStream_t stream)
{
    const float* vert = (const float*)d_in[0];
    const int*   nbr  = (const int*)d_in[1];
    const int*   deg  = (const int*)d_in[2];

    const int n      = in_sizes[2];            // 16384
    const int maxdeg = in_sizes[1] / n;
    const int d      = in_sizes[0] / n;        // 256

    int*   headlist = (int*)d_ws;                                  // n ints
    uint4* pend_g   = (uint4*)(headlist + n);                      // n uint4 (256KB)
    unsigned short* hi_g = (unsigned short*)(pend_g + n);          // n * HROW u16

    float* out      = (float*)d_out;
    float* out_tail = out + (size_t)n * (size_t)d;   // head_mask .. num_clusters

    hipLaunchKernelGGL(k_prep, dim3((n + 255) / 256), dim3(256), 0, stream,
                       nbr, deg, maxdeg, n, pend_g, hi_g);

    hipLaunchKernelGGL(k_mis, dim3(1), dim3(TPB), 0, stream,
                       nbr, deg, maxdeg, n, pend_g, hi_g, headlist, out_tail);

    const int blocks = (n * 64 + 255) / 256;   // one wave per output row
    hipLaunchKernelGGL(k_avg, dim3(blocks), dim3(256), 0, stream,
                       vert, nbr, deg, maxdeg, n, headlist, out_tail, out);
}

// Round 19
// 78.105 us; speedup vs baseline: 1.1270x; 1.1270x over previous
//
#include <hip/hip_runtime.h>
#include <cstdint>
#include <cstddef>

// Problem constants (from reference): N=16384, D=256.
#define NV 16384
#define DD 256
#define TPB 1024           // k_mis threads (16 waves), 1 vertex/thread/block
#define BLK 1024
#define PCAP 7             // in-block lower-neighbor cap (fallback exists)
#define HROW 24            // u16 slots per vertex in hi_g: [0]=count, [1..23]=higher nbrs
#define NPASS 512          // spin cap per barrier round (common case: 1 round/block)

// compiler memory barrier: forces LDS re-reads across passes WITHOUT ordering
// the loads within a pass against each other
#define CFENCE() asm volatile("" ::: "memory")

// ---------------------------------------------------------------------------
// K_prep (parallel): nbr rows are SORTED ascending (np.unique in the ref), so
// lower nbrs are a prefix and the in-block lower ones a contiguous subrange:
//   lo_b = first k with row[k] >= b ; nlo = first k with row[k] > v (== # lower)
// Packing loops then iterate ONLY the relevant short ranges (~9 avg vs 36).
//  - pend_g[v] (uint4): in-block lower nbrs (row[lo_b..nlo)) as u16 offsets
//  - hi_g[v*HROW..]: [count | 23 higher-nbr ids] (row[nlo..dv)), 3x uint4
// ---------------------------------------------------------------------------
__global__ __launch_bounds__(256)
void k_prep(const int* __restrict__ nbr, const int* __restrict__ deg,
            int maxdeg, int n, uint4* __restrict__ pend_g,
            unsigned short* __restrict__ hi_g)
{
    int v = blockIdx.x * 256 + threadIdx.x;
    if (v >= n) return;
    const int b  = v & ~(BLK - 1);
    const int dv = deg[v];
    const int* __restrict__ row = nbr + (size_t)v * (size_t)maxdeg;

    // split points in the sorted row (simple linear scans, predictable)
    int nlo = 0;
    while (nlo < dv && row[nlo] < v) ++nlo;
    int lo_b = nlo;
    while (lo_b > 0 && row[lo_b - 1] >= b) --lo_b;

    // pack in-block lower (short loop, <=7 normally)
    unsigned w0 = 0, w1 = 0, w2 = 0, w3 = 0;
    const int cnt = nlo - lo_b;
    {
        int m = cnt > PCAP ? PCAP : cnt;
        for (int i = 0; i < m; ++i) {
            unsigned val = (unsigned)(row[lo_b + i] - b);
            switch (i) {
                case 0: w0 |= val << 16; break;
                case 1: w1 |= val;       break;
                case 2: w1 |= val << 16; break;
                case 3: w2 |= val;       break;
                case 4: w2 |= val << 16; break;
                case 5: w3 |= val;       break;
                case 6: w3 |= val << 16; break;
            }
        }
    }
    // pack higher list (short loop, ~8 avg, <=23 stored)
    unsigned g0=0,g1=0,g2=0,g3=0,g4=0,g5=0,g6=0,g7=0,g8=0,g9=0,g10=0,g11=0;
    const int hic = dv - nlo;
    {
        int m = hic > HROW - 1 ? HROW - 1 : hic;
        for (int i = 0; i < m; ++i) {
            unsigned e = (unsigned)row[nlo + i];
            switch (i) {    // entry i at u16 slot 1+i: word (1+i)>>1, half (1+i)&1
                case 0:  g0  |= e << 16; break;
                case 1:  g1  |= e; break;   case 2:  g1  |= e << 16; break;
                case 3:  g2  |= e; break;   case 4:  g2  |= e << 16; break;
                case 5:  g3  |= e; break;   case 6:  g3  |= e << 16; break;
                case 7:  g4  |= e; break;   case 8:  g4  |= e << 16; break;
                case 9:  g5  |= e; break;   case 10: g5  |= e << 16; break;
                case 11: g6  |= e; break;   case 12: g6  |= e << 16; break;
                case 13: g7  |= e; break;   case 14: g7  |= e << 16; break;
                case 15: g8  |= e; break;   case 16: g8  |= e << 16; break;
                case 17: g9  |= e; break;   case 18: g9  |= e << 16; break;
                case 19: g10 |= e; break;   case 20: g10 |= e << 16; break;
                case 21: g11 |= e; break;   case 22: g11 |= e << 16; break;
            }
        }
    }
    g0 |= (unsigned)(hic > 0xffff ? 0xffff : hic);
    uint4* hq = (uint4*)(hi_g + (size_t)v * HROW);   // 48B rows, 16B-aligned
    hq[0] = make_uint4(g0, g1, g2, g3);
    hq[1] = make_uint4(g4, g5, g6, g7);
    hq[2] = make_uint4(g8, g9, g10, g11);
    w0 |= (unsigned)(cnt > 0xffff ? 0xffff : cnt);
    pend_g[v] = make_uint4(w0, w1, w2, w3);
}

// ---------------------------------------------------------------------------
// K_mis: lexicographic greedy MIS, single WG of 1024 threads (16 waves), PUSH.
// st: 0=unknown, 1=head, 2=nonhead (monotone -> LDS races benign).
// Waves spin until all their lanes are decided (in-block deps point strictly
// to lower indices -> provable progress), so a block needs ~ONE barrier.
// F-protocol kept as safety net (NPASS spin cap). 15-variant-validated floor:
// ~51.5us; probe style/count, pass count, phase count, barrier count all null.
// ---------------------------------------------------------------------------
__global__ __launch_bounds__(TPB, 4)
void k_mis(const int* __restrict__ nbr, const int* __restrict__ deg,
           int maxdeg, int n,
           const uint4* __restrict__ pend_g, const unsigned short* __restrict__ hi_g,
           int* __restrict__ headlist, float* __restrict__ out_tail)
{
    __shared__ __align__(16) unsigned char st[NV];
    __shared__ int s_ws[TPB / 64];
    __shared__ int F[3];
    const int t    = threadIdx.x;
    const int lane = t & 63;
    const int wid  = t >> 6;

    ((uint4*)st)[t] = make_uint4(0u, 0u, 0u, 0u);   // 1024*16B == NV
    if (t < 3) F[t] = 0;
    __syncthreads();

    // prefetch block 0 (pend + hi row + deg), register double-buffered
    uint4 pv = make_uint4(0,0,0,0), h0 = pv, h1 = pv, h2 = pv;
    int   dv = 0;
    if (t < n) {
        pv = pend_g[t];
        const uint4* hp = (const uint4*)(hi_g + (size_t)t * HROW);
        h0 = hp[0]; h1 = hp[1]; h2 = hp[2];
        dv = deg[t];
    }
    int r = 0;

    for (int b = 0; b < n; b += BLK) {
        const int v = b + t;
        // prefetch next block; stays in flight across the drain-free barriers
        uint4 pn = make_uint4(0,0,0,0), n0 = pn, n1 = pn, n2 = pn;
        int   dn = 0;
        {
            int vn = b + BLK + t;
            if (vn < n) {
                pn = pend_g[vn];
                const uint4* hp = (const uint4*)(hi_g + (size_t)vn * HROW);
                n0 = hp[0]; n1 = hp[1]; n2 = hp[2];
                dn = deg[vn];
            }
        }

        const int np = pv.x & 0xffff;
        const int e0 = pv.x >> 16,    e1 = pv.y & 0xffff, e2 = pv.y >> 16;
        const int e3 = pv.z & 0xffff, e4 = pv.z >> 16;
        const int e5 = pv.w & 0xffff, e6 = pv.w >> 16;
        const int hic = (int)(h0.x & 0xffff);
        const int* __restrict__ row = nbr + (size_t)v * (size_t)maxdeg;

        int my = (v < n) ? 0 : 2;
        for (;; ++r) {
            if (t == 0) F[(r + 1) % 3] = 0;
            for (int pass = 0; pass < NPASS; ++pass) {
                if (my == 0) {
                    int qv = st[v];
                    int q0 = 0, q1 = 0, q2 = 0, q3 = 0, q4 = 0, q5 = 0, q6 = 0;
                    if (np > 0 && np <= PCAP) {
                        q0 = st[b + e0]; q1 = st[b + e1]; q2 = st[b + e2];
                        q3 = st[b + e3]; q4 = st[b + e4]; q5 = st[b + e5];
                        q6 = st[b + e6];
                    }
                    if (qv != 0) { my = 2; }
                    else {
                        bool anyH = false; int undec = 0;
                        if (np <= PCAP) {
                            if (np > 0) { anyH |= (q0 == 1); undec += (q0 == 0); }
                            if (np > 1) { anyH |= (q1 == 1); undec += (q1 == 0); }
                            if (np > 2) { anyH |= (q2 == 1); undec += (q2 == 0); }
                            if (np > 3) { anyH |= (q3 == 1); undec += (q3 == 0); }
                            if (np > 4) { anyH |= (q4 == 1); undec += (q4 == 0); }
                            if (np > 5) { anyH |= (q5 == 1); undec += (q5 == 0); }
                            if (np > 6) { anyH |= (q6 == 1); undec += (q6 == 0); }
                        } else {
                            for (int k = 0; k < dv; ++k) {
                                int j = row[k];
                                if (j >= b && j < v) {
                                    int q = st[j];
                                    anyH |= (q == 1); undec += (q == 0);
                                }
                            }
                        }
                        if (anyH) { my = 2; st[v] = 2; }
                        else if (undec == 0) {
                            my = 1;
                            st[v] = 1;
                            if (hic <= HROW - 1) {
                                #define PUSHE(word, sh, k) if ((k) < hic) st[((word) >> (sh)) & 0xffffu] = 2
                                PUSHE(h0.x,16, 0); PUSHE(h0.y, 0, 1); PUSHE(h0.y,16, 2);
                                PUSHE(h0.z, 0, 3); PUSHE(h0.z,16, 4); PUSHE(h0.w, 0, 5);
                                PUSHE(h0.w,16, 6);
                                PUSHE(h1.x, 0, 7); PUSHE(h1.x,16, 8); PUSHE(h1.y, 0, 9);
                                PUSHE(h1.y,16,10); PUSHE(h1.z, 0,11); PUSHE(h1.z,16,12);
                                PUSHE(h1.w, 0,13); PUSHE(h1.w,16,14);
                                PUSHE(h2.x, 0,15); PUSHE(h2.x,16,16); PUSHE(h2.y, 0,17);
                                PUSHE(h2.y,16,18); PUSHE(h2.z, 0,19); PUSHE(h2.z,16,20);
                                PUSHE(h2.w, 0,21); PUSHE(h2.w,16,22);
                                #undef PUSHE
                            } else {
                                for (int k = 0; k < dv; ++k) {
                                    int j = row[k];
                                    if (j > v) st[j] = 2;
                                }
                            }
                        }
                    }
                }
                if (__ballot(my == 0) == 0ULL) break;   // wave done -> barrier
                CFENCE();   // force genuine LDS re-reads next pass
            }
            if (my == 0) F[r % 3] = 1;   // only if spin cap was exhausted
            // drain-free barrier: LDS visible, global prefetch stays in flight
            asm volatile("s_waitcnt lgkmcnt(0)\n\ts_barrier" ::: "memory");
            if (F[r % 3] == 0) { ++r; break; }
        }
        pv = pn; h0 = n0; h1 = n1; h2 = n2; dv = dn;
    }

    // ---- epilogue: count heads, scan, emit headlist / head_mask / count ----
    uint4 qq = ((const uint4*)st)[t];          // thread t owns bytes [16t,16t+16)
    int cnt = __popc(qq.x & 0x01010101u) + __popc(qq.y & 0x01010101u)
            + __popc(qq.z & 0x01010101u) + __popc(qq.w & 0x01010101u);
    int c = cnt;
    #pragma unroll
    for (int off = 1; off < 64; off <<= 1) {
        int x = __shfl_up(c, off);
        if (lane >= off) c += x;
    }
    if (lane == 63) s_ws[wid] = c;
    __syncthreads();
    int wexcl = 0, tot = 0;
    #pragma unroll
    for (int w = 0; w < TPB / 64; ++w) {
        int s = s_ws[w];
        tot += s;
        if (w < wid) wexcl += s;
    }
    int excl = wexcl + (c - cnt);
    #pragma unroll
    for (int i = 0; i < 16; ++i) {
        int v = t * 16 + i;
        if (st[v] == 1) { headlist[excl] = v; ++excl; }
    }
    for (int i = t; i < NV / 4; i += TPB) {
        unsigned w = ((const unsigned*)st)[i];
        float4 f;
        f.x = (float)(w & 1u);         f.y = (float)((w >> 8) & 1u);
        f.z = (float)((w >> 16) & 1u); f.w = (float)((w >> 24) & 1u);
        ((float4*)out_tail)[i] = f;
    }
    if (t == 0) out_tail[n] = (float)tot;
}

// ---------------------------------------------------------------------------
// K_avg (fused owner+avg): one 64-lane wave per output row.
// Rows are SORTED, so owner(j) = min adjacent head = FIRST head in row(j):
// walk row(j) from the front, break at the first head u; member iff u == h.
// (The loop always terminates at u == h since h is adjacent to j and a head.)
// Waves [tot,n): zero-fill the row (replaces the memset).
// ---------------------------------------------------------------------------
__global__ __launch_bounds__(256)
void k_avg(const float* __restrict__ vert, const int* __restrict__ nbr,
           const int* __restrict__ deg, int maxdeg, int n,
           const int* __restrict__ headlist,
           const float* __restrict__ tail, float* __restrict__ out)
{
    const int w    = (blockIdx.x * 256 + threadIdx.x) >> 6;
    const int lane = threadIdx.x & 63;
    if (w >= n) return;
    const int tot  = (int)tail[n];
    if (w >= tot) {
        reinterpret_cast<float4*>(out + (size_t)w * DD)[lane] = make_float4(0.f, 0.f, 0.f, 0.f);
        return;
    }
    const int h = headlist[w];

    const int dh = deg[h];
    const int* __restrict__ row = nbr + (size_t)h * (size_t)maxdeg;

    float4 acc = reinterpret_cast<const float4*>(vert + (size_t)h * DD)[lane];
    int cnt = 1;

    for (int k0 = 0; k0 < dh; k0 += 64) {
        int k = k0 + lane;
        int j = (k < dh) ? row[k] : -1;
        bool mem = false;
        if (j > h && tail[j] == 0.0f) {        // nonhead, higher candidate
            // owner test: first head in j's sorted row must be h
            const int dj = deg[j];
            const int* __restrict__ rj = nbr + (size_t)j * (size_t)maxdeg;
            for (int kk = 0; kk < dj; ++kk) {
                int u = rj[kk];
                if (tail[u] != 0.0f) { mem = (u == h); break; }
            }
        }
        unsigned long long m = __ballot(mem);
        cnt += __popcll(m);
        while (m) {
            int bit = __ffsll((long long)m) - 1;
            m &= (m - 1);
            int jj = __shfl(j, bit);
            float4 rr = reinterpret_cast<const float4*>(vert + (size_t)jj * DD)[lane];
            acc.x += rr.x; acc.y += rr.y; acc.z += rr.z; acc.w += rr.w;
        }
    }
    const float inv = 1.0f / (float)cnt;
    float4 res;
    res.x = acc.x * inv; res.y = acc.y * inv;
    res.z = acc.z * inv; res.w = acc.w * inv;
    reinterpret_cast<float4*>(out + (size_t)w * DD)[lane] = res;
}

// ---------------------------------------------------------------------------
extern "C" void kernel_launch(void* const* d_in, const int* in_sizes, int n_in,
                              void* d_out, int out_size, void* d_ws, size_t ws_size,
                              hipStream_t stream)
{
    const float* vert = (const float*)d_in[0];
    const int*   nbr  = (const int*)d_in[1];
    const int*   deg  = (const int*)d_in[2];

    const int n      = in_sizes[2];            // 16384
    const int maxdeg = in_sizes[1] / n;
    const int d      = in_sizes[0] / n;        // 256

    int*   headlist = (int*)d_ws;                                  // n ints
    uint4* pend_g   = (uint4*)(headlist + n);                      // n uint4 (256KB)
    unsigned short* hi_g = (unsigned short*)(pend_g + n);          // n * HROW u16

    float* out      = (float*)d_out;
    float* out_tail = out + (size_t)n * (size_t)d;   // head_mask .. num_clusters

    hipLaunchKernelGGL(k_prep, dim3((n + 255) / 256), dim3(256), 0, stream,
                       nbr, deg, maxdeg, n, pend_g, hi_g);

    hipLaunchKernelGGL(k_mis, dim3(1), dim3(TPB), 0, stream,
                       nbr, deg, maxdeg, n, pend_g, hi_g, headlist, out_tail);

    const int blocks = (n * 64 + 255) / 256;   // one wave per output row
    hipLaunchKernelGGL(k_avg, dim3(blocks), dim3(256), 0, stream,
                       vert, nbr, deg, maxdeg, n, headlist, out_tail, out);
}